// Round 2
// baseline (155.242 us; speedup 1.0000x reference)
//
#include <hip/hip_runtime.h>
#include <hip/hip_bf16.h>
#include <math.h>

#define BATCH   4
#define NATOMS  2048
#define MNEIGH  100
#define NFEAT   42
#define H1      64
#define H2      32

__device__ __forceinline__ float softplus_f(float z) {
    // log(1 + exp(z)), numerically stable
    if (z > 20.f) return z;
    return log1pf(expf(z));
}

__device__ __forceinline__ float sigmoid_f(float z) {
    return 1.f / (1.f + expf(-z));
}

// ---------------------------------------------------------------------------
// Kernel 1: per-atom MLP forward + analytic dE/dx chain.
// 256 threads = 4 waves; each wave handles 4 atoms (16 atoms/block).
// Lane h owns hidden unit h. Weights staged in LDS once per block.
// ---------------------------------------------------------------------------
__global__ __launch_bounds__(256) void mlp_kernel(
    const float* __restrict__ image,
    const float* __restrict__ W0, const float* __restrict__ b0,
    const float* __restrict__ W1, const float* __restrict__ b1,
    const float* __restrict__ W2, const float* __restrict__ b2,
    float* __restrict__ Ei_out,      // [B*N]
    float* __restrict__ dE)          // [B*N, F]
{
    __shared__ float sW0[H1 * NFEAT];   // 2688
    __shared__ float sW1[H2 * H1];      // 2048
    __shared__ float sW2[H2];
    __shared__ float sb0[H1];
    __shared__ float sb1[H2];
    __shared__ float sImg[4][NFEAT];
    __shared__ float sL0[4][H1];
    __shared__ float sG2[4][H2];
    __shared__ float sG1[4][H1];

    const int tid = threadIdx.x;
    for (int i = tid; i < H1 * NFEAT; i += 256) sW0[i] = W0[i];
    for (int i = tid; i < H2 * H1;   i += 256) sW1[i] = W1[i];
    if (tid < H2) { sW2[tid] = W2[tid]; sb1[tid] = b1[tid]; }
    if (tid < H1) sb0[tid] = b0[tid];
    const float bias2 = b2[0];
    __syncthreads();

    const int wave = tid >> 6;
    const int lane = tid & 63;

    for (int it = 0; it < 4; ++it) {
        const int ga = blockIdx.x * 16 + wave * 4 + it;   // global atom index

        // stage image row for this wave's atom
        if (lane < NFEAT) sImg[wave][lane] = image[(size_t)ga * NFEAT + lane];
        __syncthreads();

        // z0[h] = b0[h] + img . W0[h,:]
        float z0 = sb0[lane];
        #pragma unroll
        for (int f = 0; f < NFEAT; ++f)
            z0 = fmaf(sImg[wave][f], sW0[lane * NFEAT + f], z0);
        const float L0 = softplus_f(z0);
        const float d0 = sigmoid_f(z0);
        sL0[wave][lane] = L0;
        __syncthreads();

        // z1[h2] = b1[h2] + L0 . W1[h2,:]   (lanes < 32)
        float d1 = 0.f, ei = 0.f;
        if (lane < H2) {
            float z1 = sb1[lane];
            #pragma unroll
            for (int h = 0; h < H1; ++h)
                z1 = fmaf(sL0[wave][h], sW1[lane * H1 + h], z1);
            const float L1 = softplus_f(z1);
            d1 = sigmoid_f(z1);
            ei = L1 * sW2[lane];
        }
        // Ei = sum(L1 * W2) + b2  (wave reduce; lanes >= 32 contribute 0)
        #pragma unroll
        for (int off = 32; off > 0; off >>= 1) ei += __shfl_down(ei, off, 64);
        if (lane == 0) Ei_out[ga] = ei + bias2;

        // g2 = d1 * W2
        if (lane < H2) sG2[wave][lane] = d1 * sW2[lane];
        __syncthreads();

        // g1[h] = (sum_h2 g2[h2] * W1[h2,h]) * d0[h]
        float g1 = 0.f;
        #pragma unroll
        for (int h2 = 0; h2 < H2; ++h2)
            g1 = fmaf(sG2[wave][h2], sW1[h2 * H1 + lane], g1);
        g1 *= d0;
        sG1[wave][lane] = g1;
        __syncthreads();

        // dE[f] = sum_h g1[h] * W0[h,f]   (lanes < 42)
        if (lane < NFEAT) {
            float s = 0.f;
            #pragma unroll
            for (int h = 0; h < H1; ++h)
                s = fmaf(sG1[wave][h], sW0[h * NFEAT + lane], s);
            dE[(size_t)ga * NFEAT + lane] = s;
        }
        __syncthreads();   // protect LDS reuse next iteration
    }
}

// ---------------------------------------------------------------------------
// Kernel 2: Etot[b] = sum_n Ei[b,n]  (deterministic two-stage reduce)
// ---------------------------------------------------------------------------
__global__ __launch_bounds__(256) void etot_kernel(
    const float* __restrict__ Ei, float* __restrict__ Etot)
{
    const int b = blockIdx.x;
    const int tid = threadIdx.x;
    float s = 0.f;
    for (int n = tid; n < NATOMS; n += 256) s += Ei[(size_t)b * NATOMS + n];
    #pragma unroll
    for (int off = 32; off > 0; off >>= 1) s += __shfl_down(s, off, 64);
    __shared__ float rb[4];
    if ((tid & 63) == 0) rb[tid >> 6] = s;
    __syncthreads();
    if (tid == 0) Etot[b] = rb[0] + rb[1] + rb[2] + rb[3];
}

// ---------------------------------------------------------------------------
// Kernel 3: force[b,n,c] = sum_m sum_f dE[b, nbr-1, f] * dfeat[b,n,m,f,c]
// One block per (b,n). Gathered dE rows staged in LDS; dfeat (50.4 KB/atom,
// contiguous) streamed once. This kernel carries ~all the HBM traffic.
// ---------------------------------------------------------------------------
__global__ __launch_bounds__(256) void force_kernel(
    const float* __restrict__ dfeat,
    const int*   __restrict__ neighbor,
    const float* __restrict__ dE,
    float* __restrict__ force)
{
    __shared__ float sdE[MNEIGH * NFEAT];   // 4200 floats = 16.8 KB
    const int ga  = blockIdx.x;             // b*N + n
    const int b   = ga >> 11;               // N = 2048
    const int tid = threadIdx.x;

    const int* __restrict__ nbr = neighbor + (size_t)ga * MNEIGH;
    for (int j = tid; j < MNEIGH * NFEAT; j += 256) {
        const int m = j / NFEAT;
        const int f = j - m * NFEAT;
        const int nb = nbr[m];
        sdE[j] = (nb > 0) ? dE[((size_t)b * NATOMS + (nb - 1)) * NFEAT + f] : 0.f;
    }
    __syncthreads();

    const float* __restrict__ dfb = dfeat + (size_t)ga * (MNEIGH * NFEAT * 3);
    float a0 = 0.f, a1 = 0.f, a2 = 0.f;
    for (int p = tid; p < MNEIGH * NFEAT; p += 256) {
        const float w = sdE[p];
        const float* d3 = dfb + p * 3;
        a0 = fmaf(d3[0], w, a0);
        a1 = fmaf(d3[1], w, a1);
        a2 = fmaf(d3[2], w, a2);
    }

    // block-reduce the 3 partial sums
    #pragma unroll
    for (int off = 32; off > 0; off >>= 1) {
        a0 += __shfl_down(a0, off, 64);
        a1 += __shfl_down(a1, off, 64);
        a2 += __shfl_down(a2, off, 64);
    }
    __shared__ float rbuf[4][3];
    const int wave = tid >> 6, lane = tid & 63;
    if (lane == 0) { rbuf[wave][0] = a0; rbuf[wave][1] = a1; rbuf[wave][2] = a2; }
    __syncthreads();
    if (tid < 3)
        force[(size_t)ga * 3 + tid] = rbuf[0][tid] + rbuf[1][tid] + rbuf[2][tid] + rbuf[3][tid];
}

// ---------------------------------------------------------------------------
extern "C" void kernel_launch(void* const* d_in, const int* in_sizes, int n_in,
                              void* d_out, int out_size, void* d_ws, size_t ws_size,
                              hipStream_t stream) {
    const float* image = (const float*)d_in[0];
    const float* dfeat = (const float*)d_in[1];
    // d_in[2] = Egroup_weight (unused by reference), d_in[3] = divider (unused)
    const float* W0 = (const float*)d_in[4];
    const float* b0 = (const float*)d_in[5];
    const float* W1 = (const float*)d_in[6];
    const float* b1 = (const float*)d_in[7];
    const float* W2 = (const float*)d_in[8];
    const float* b2 = (const float*)d_in[9];
    const int*   neighbor = (const int*)d_in[10];

    float* out   = (float*)d_out;
    float* Etot  = out;                          // [B,1]   -> 4
    float* Ei    = out + BATCH;                  // [B,N,1] -> 8192
    float* force = out + BATCH + BATCH * NATOMS; // [B,N,3] -> 24576
    float* dE    = (float*)d_ws;                 // [B,N,F] floats in workspace

    mlp_kernel<<<BATCH * NATOMS / 16, 256, 0, stream>>>(
        image, W0, b0, W1, b1, W2, b2, Ei, dE);
    etot_kernel<<<BATCH, 256, 0, stream>>>(Ei, Etot);
    force_kernel<<<BATCH * NATOMS, 256, 0, stream>>>(dfeat, neighbor, dE, force);
}

// Round 3
// 151.178 us; speedup vs baseline: 1.0269x; 1.0269x over previous
//
#include <hip/hip_runtime.h>
#include <hip/hip_bf16.h>
#include <math.h>

#define BATCH   4
#define NATOMS  2048
#define MNEIGH  100
#define NFEAT   42
#define H1      64
#define H2      32
#define NPAIR   (MNEIGH * NFEAT)        // 4200
#define NGROUP  (NPAIR / 4)             // 1050 groups of 4 (m,f) pairs

__device__ __forceinline__ float softplus_f(float z) {
    if (z > 20.f) return z;
    return log1pf(expf(z));
}

__device__ __forceinline__ float sigmoid_f(float z) {
    return 1.f / (1.f + expf(-z));
}

// ---------------------------------------------------------------------------
// Kernel 1: per-atom MLP forward + analytic dE/dx chain.
// 256 threads = 4 waves; each wave handles 4 atoms serially, NO in-loop
// barriers: all cross-lane data moves via __shfl (compile-time lane index ->
// v_readlane), weights live in LDS in both layouts so every in-loop LDS read
// is lane-consecutive (conflict-free).
// ---------------------------------------------------------------------------
__global__ __launch_bounds__(256) void mlp_kernel(
    const float* __restrict__ image,
    const float* __restrict__ W0, const float* __restrict__ b0,
    const float* __restrict__ W1, const float* __restrict__ b1,
    const float* __restrict__ W2, const float* __restrict__ b2,
    float* __restrict__ Ei_out,      // [B*N]
    float* __restrict__ dE)          // [B*N, F]
{
    __shared__ float sW0 [H1 * NFEAT];   // [h][f]  (for dE pass)
    __shared__ float sW0T[NFEAT * H1];   // [f][h]  (for z0 pass)
    __shared__ float sW1 [H2 * H1];      // [h2][h] (for g1 pass)
    __shared__ float sW1T[H1 * H2];      // [h][h2] (for z1 pass)
    __shared__ float sW2[H2];
    __shared__ float sb0[H1];
    __shared__ float sb1[H2];

    const int tid = threadIdx.x;
    for (int i = tid; i < H1 * NFEAT; i += 256) {
        const float v = W0[i];
        sW0[i] = v;
        const int h = i / NFEAT, f = i - h * NFEAT;
        sW0T[f * H1 + h] = v;
    }
    for (int i = tid; i < H2 * H1; i += 256) {
        const float v = W1[i];
        sW1[i] = v;
        const int h2 = i >> 6, h = i & 63;
        sW1T[h * H2 + h2] = v;
    }
    if (tid < H2) { sW2[tid] = W2[tid]; sb1[tid] = b1[tid]; }
    if (tid < H1) sb0[tid] = b0[tid];
    const float bias2 = b2[0];
    __syncthreads();    // the ONLY barrier

    const int wave = tid >> 6;
    const int lane = tid & 63;
    const int l2   = lane & 31;                      // duplicated H2 index
    const int lf   = (lane < NFEAT) ? lane : NFEAT - 1; // clamped F index

    for (int it = 0; it < 4; ++it) {
        const int ga = blockIdx.x * 16 + wave * 4 + it;

        float img = 0.f;
        if (lane < NFEAT) img = image[(size_t)ga * NFEAT + lane];

        // z0[h=lane] = b0 + sum_f img[f] * W0[h][f]
        float z0a = sb0[lane], z0b = 0.f;
        #pragma unroll
        for (int f = 0; f < NFEAT; f += 2) {
            z0a = fmaf(__shfl(img, f,     64), sW0T[f * H1 + lane],       z0a);
            z0b = fmaf(__shfl(img, f + 1, 64), sW0T[(f + 1) * H1 + lane], z0b);
        }
        const float z0 = z0a + z0b;
        const float L0 = softplus_f(z0);
        const float d0 = sigmoid_f(z0);

        // z1[h2=l2] = b1 + sum_h L0[h] * W1[h2][h]   (upper half duplicates)
        float z1a = sb1[l2], z1b = 0.f;
        #pragma unroll
        for (int h = 0; h < H1; h += 2) {
            z1a = fmaf(__shfl(L0, h,     64), sW1T[h * H2 + l2],       z1a);
            z1b = fmaf(__shfl(L0, h + 1, 64), sW1T[(h + 1) * H2 + l2], z1b);
        }
        const float z1 = z1a + z1b;
        const float L1 = softplus_f(z1);
        const float d1 = sigmoid_f(z1);
        const float w2 = sW2[l2];

        // Ei = sum_h2 L1*W2 + b2  (reduce lanes 0..31 into lane 0)
        float ei = L1 * w2;
        #pragma unroll
        for (int off = 16; off > 0; off >>= 1) ei += __shfl_down(ei, off, 64);
        if (lane == 0) Ei_out[ga] = ei + bias2;

        // g1[h=lane] = d0 * sum_h2 (d1*W2)[h2] * W1[h2][h]
        const float g2v = d1 * w2;
        float g1a = 0.f, g1b = 0.f;
        #pragma unroll
        for (int h2 = 0; h2 < H2; h2 += 2) {
            g1a = fmaf(__shfl(g2v, h2,     64), sW1[h2 * H1 + lane],       g1a);
            g1b = fmaf(__shfl(g2v, h2 + 1, 64), sW1[(h2 + 1) * H1 + lane], g1b);
        }
        const float g1 = (g1a + g1b) * d0;

        // dE[f=lane] = sum_h g1[h] * W0[h][f]
        float sa = 0.f, sb = 0.f;
        #pragma unroll
        for (int h = 0; h < H1; h += 2) {
            sa = fmaf(__shfl(g1, h,     64), sW0[h * NFEAT + lf],       sa);
            sb = fmaf(__shfl(g1, h + 1, 64), sW0[(h + 1) * NFEAT + lf], sb);
        }
        if (lane < NFEAT) dE[(size_t)ga * NFEAT + lane] = sa + sb;
    }
}

// ---------------------------------------------------------------------------
// Kernel 2: Etot[b] = sum_n Ei[b,n]
// ---------------------------------------------------------------------------
__global__ __launch_bounds__(256) void etot_kernel(
    const float* __restrict__ Ei, float* __restrict__ Etot)
{
    const int b = blockIdx.x;
    const int tid = threadIdx.x;
    float s = 0.f;
    for (int n = tid; n < NATOMS; n += 256) s += Ei[(size_t)b * NATOMS + n];
    #pragma unroll
    for (int off = 32; off > 0; off >>= 1) s += __shfl_down(s, off, 64);
    __shared__ float rb[4];
    if ((tid & 63) == 0) rb[tid >> 6] = s;
    __syncthreads();
    if (tid == 0) Etot[b] = rb[0] + rb[1] + rb[2] + rb[3];
}

// ---------------------------------------------------------------------------
// Kernel 3: force[b,n,c] = sum_m sum_f dE[b, nbr-1, f] * dfeat[b,n,m,f,c]
// One block per (b,n). dfeat streamed as float4 (3 x dwordx4 per 4 pairs,
// 48 B/lane, 16B-aligned: 50400 B/atom = 3150 float4). Weights read as
// float4 from LDS. Carries ~all HBM traffic (413 MB read once).
// ---------------------------------------------------------------------------
__global__ __launch_bounds__(256) void force_kernel(
    const float* __restrict__ dfeat,
    const int*   __restrict__ neighbor,
    const float* __restrict__ dE,
    float* __restrict__ force)
{
    __shared__ float4 sdE4[NGROUP];         // 4200 floats = 16.8 KB
    float* sdE = (float*)sdE4;
    const int ga  = blockIdx.x;             // b*N + n
    const int b   = ga >> 11;               // N = 2048
    const int tid = threadIdx.x;

    const int* __restrict__ nbr = neighbor + (size_t)ga * MNEIGH;
    for (int j = tid; j < NPAIR; j += 256) {
        const int m = j / NFEAT;
        const int f = j - m * NFEAT;
        const int nb = nbr[m];
        sdE[j] = (nb > 0) ? dE[((size_t)b * NATOMS + (nb - 1)) * NFEAT + f] : 0.f;
    }
    __syncthreads();

    const float4* __restrict__ dfb4 =
        (const float4*)(dfeat + (size_t)ga * (NPAIR * 3));
    float a0 = 0.f, a1 = 0.f, a2 = 0.f;
    for (int g = tid; g < NGROUP; g += 256) {
        const float4 w  = sdE4[g];
        const float4 v0 = dfb4[3 * g];
        const float4 v1 = dfb4[3 * g + 1];
        const float4 v2 = dfb4[3 * g + 2];
        a0 = fmaf(v0.x, w.x, a0); a1 = fmaf(v0.y, w.x, a1); a2 = fmaf(v0.z, w.x, a2);
        a0 = fmaf(v0.w, w.y, a0); a1 = fmaf(v1.x, w.y, a1); a2 = fmaf(v1.y, w.y, a2);
        a0 = fmaf(v1.z, w.z, a0); a1 = fmaf(v1.w, w.z, a1); a2 = fmaf(v2.x, w.z, a2);
        a0 = fmaf(v2.y, w.w, a0); a1 = fmaf(v2.z, w.w, a1); a2 = fmaf(v2.w, w.w, a2);
    }

    // block-reduce the 3 partial sums
    #pragma unroll
    for (int off = 32; off > 0; off >>= 1) {
        a0 += __shfl_down(a0, off, 64);
        a1 += __shfl_down(a1, off, 64);
        a2 += __shfl_down(a2, off, 64);
    }
    __shared__ float rbuf[4][3];
    const int wave = tid >> 6, lane = tid & 63;
    if (lane == 0) { rbuf[wave][0] = a0; rbuf[wave][1] = a1; rbuf[wave][2] = a2; }
    __syncthreads();
    if (tid < 3)
        force[(size_t)ga * 3 + tid] = rbuf[0][tid] + rbuf[1][tid] + rbuf[2][tid] + rbuf[3][tid];
}

// ---------------------------------------------------------------------------
extern "C" void kernel_launch(void* const* d_in, const int* in_sizes, int n_in,
                              void* d_out, int out_size, void* d_ws, size_t ws_size,
                              hipStream_t stream) {
    const float* image = (const float*)d_in[0];
    const float* dfeat = (const float*)d_in[1];
    // d_in[2] = Egroup_weight (unused by reference), d_in[3] = divider (unused)
    const float* W0 = (const float*)d_in[4];
    const float* b0 = (const float*)d_in[5];
    const float* W1 = (const float*)d_in[6];
    const float* b1 = (const float*)d_in[7];
    const float* W2 = (const float*)d_in[8];
    const float* b2 = (const float*)d_in[9];
    const int*   neighbor = (const int*)d_in[10];

    float* out   = (float*)d_out;
    float* Etot  = out;                          // [B,1]   -> 4
    float* Ei    = out + BATCH;                  // [B,N,1] -> 8192
    float* force = out + BATCH + BATCH * NATOMS; // [B,N,3] -> 24576
    float* dE    = (float*)d_ws;                 // [B,N,F] floats in workspace

    mlp_kernel<<<BATCH * NATOMS / 16, 256, 0, stream>>>(
        image, W0, b0, W1, b1, W2, b2, Ei, dE);
    etot_kernel<<<BATCH, 256, 0, stream>>>(Ei, Etot);
    force_kernel<<<BATCH * NATOMS, 256, 0, stream>>>(dfeat, neighbor, dE, force);
}